// Round 1
// baseline (98.049 us; speedup 1.0000x reference)
//
#include <hip/hip_runtime.h>
#include <hip/hip_bf16.h>
#include <stdint.h>
#include <stddef.h>

#define NSEQ  4096
#define DM    1024
#define NHEAD 16
#define DHEAD 64
#define WIN   64

using short8 = __attribute__((ext_vector_type(8))) short;
using f32x4  = __attribute__((ext_vector_type(4))) float;

#define GLOBAL_AS __attribute__((address_space(1)))
#define LDS_AS    __attribute__((address_space(3)))

__device__ __forceinline__ unsigned short f2bf(float f) {
  union { float f; unsigned int u; } v; v.f = f;
  unsigned int r = v.u + 0x7FFFu + ((v.u >> 16) & 1u);
  return (unsigned short)(r >> 16);
}

__device__ __forceinline__ void gload_lds16(void* lds, const void* g) {
  __builtin_amdgcn_global_load_lds((const GLOBAL_AS unsigned int*)g,
                                   (LDS_AS unsigned int*)lds, 16, 0, 0);
}

// ---------------- fp32 -> bf16 conversion (vectorized) ----------------
__global__ void cvt_kernel(const float* __restrict__ src,
                           unsigned short* __restrict__ dst, int n4) {
  int i = blockIdx.x * blockDim.x + threadIdx.x;
  if (i < n4) {
    float4 f = ((const float4*)src)[i];
    ushort4 o;
    o.x = f2bf(f.x); o.y = f2bf(f.y); o.z = f2bf(f.z); o.w = f2bf(f.w);
    ((ushort4*)dst)[i] = o;
  }
}

// ---------------- GEMM: C[M,N] = A[M,K] * B[N,K]^T + bias ----------------
// A, B bf16 K-major. 128x128 tile, BK=32, 4 waves (2x2 of 64x64), 16x16x32 MFMA.
// EPI 0: scatter epilogue -> Q (scaled), K, V^T  (QKV projection)
// EPI 1: plain fp32 + bias -> Cf                 (output projection)
template<int EPI>
__global__ __launch_bounds__(256)
void gemm_bt(const unsigned short* __restrict__ A,
             const unsigned short* __restrict__ B,
             const float* __restrict__ bias,
             float* __restrict__ Cf,
             unsigned short* __restrict__ qo,
             unsigned short* __restrict__ ko,
             unsigned short* __restrict__ vo,
             int M, int N, int K) {
  __shared__ short As[2][128 * 32];
  __shared__ short Bs[2][128 * 32];

  const int nbn = N >> 7;
  const int bm  = blockIdx.x / nbn;
  const int bn  = blockIdx.x % nbn;
  const int tid = threadIdx.x;
  const int w   = tid >> 6;
  const int l   = tid & 63;
  const int wr  = w >> 1, wc = w & 1;
  const int l15 = l & 15, l4 = l >> 4;

  const int m0 = bm << 7;
  const int n0 = bn << 7;

  f32x4 acc[4][4] = {};

  const int nkt = K >> 5;

  auto stage = [&](int buf, int kt) {
    const int kbase = kt << 5;
#pragma unroll
    for (int r = 0; r < 2; ++r) {
      const int c   = r * 4 + w;          // 16-row chunk index (0..7)
      const int row = c * 16 + (l >> 2);
      const int ke  = (l & 3) << 3;       // k element offset 0/8/16/24
      gload_lds16(&As[buf][c * 512 + l * 8],
                  A + (size_t)(m0 + row) * K + kbase + ke);
      gload_lds16(&Bs[buf][c * 512 + l * 8],
                  B + (size_t)(n0 + row) * K + kbase + ke);
    }
  };

  stage(0, 0);
  int cur = 0;
  for (int kt = 0; kt < nkt; ++kt) {
    __syncthreads();                       // stage(cur) complete; prior compute done
    if (kt + 1 < nkt) stage(cur ^ 1, kt + 1);
    short8 a[4], b[4];
#pragma unroll
    for (int mi = 0; mi < 4; ++mi)
      a[mi] = *(const short8*)&As[cur][(wr * 64 + mi * 16 + l15) * 32 + l4 * 8];
#pragma unroll
    for (int ni = 0; ni < 4; ++ni)
      b[ni] = *(const short8*)&Bs[cur][(wc * 64 + ni * 16 + l15) * 32 + l4 * 8];
#pragma unroll
    for (int mi = 0; mi < 4; ++mi)
#pragma unroll
      for (int ni = 0; ni < 4; ++ni)
        acc[mi][ni] = __builtin_amdgcn_mfma_f32_16x16x32_bf16(a[mi], b[ni], acc[mi][ni], 0, 0, 0);
    cur ^= 1;
  }

  if (EPI == 0) {
    // n decomposes as (s, h, d): s = n>>10 (0=Q,1=K,2=V), h = (n>>6)&15, d = n&63
#pragma unroll
    for (int ni = 0; ni < 4; ++ni) {
      const int n  = n0 + wc * 64 + ni * 16 + l15;
      const float bv = bias[n];
      const int region = n >> 10;   // uniform across block (128 | 1024)
#pragma unroll
      for (int mi = 0; mi < 4; ++mi) {
        const int mb = m0 + wr * 64 + mi * 16 + l4 * 4;
        if (region == 0) {
          const int h = (n >> 6) & 15, d = n & 63;
#pragma unroll
          for (int r = 0; r < 4; ++r)
            qo[((size_t)(h * NSEQ + mb + r)) * DHEAD + d] =
                f2bf((acc[mi][ni][r] + bv) * 0.125f);
        } else if (region == 1) {
          const int nn = n - 1024;
          const int h = nn >> 6, d = nn & 63;
#pragma unroll
          for (int r = 0; r < 4; ++r)
            ko[((size_t)(h * NSEQ + mb + r)) * DHEAD + d] =
                f2bf(acc[mi][ni][r] + bv);
        } else {
          const int nn = n - 2048;    // = h*64 + d
          ushort4 pk;
          pk.x = f2bf(acc[mi][ni][0] + bv);
          pk.y = f2bf(acc[mi][ni][1] + bv);
          pk.z = f2bf(acc[mi][ni][2] + bv);
          pk.w = f2bf(acc[mi][ni][3] + bv);
          *(ushort4*)&vo[(size_t)nn * NSEQ + mb] = pk;   // V^T: [h*64+d][m]
        }
      }
    }
  } else {
#pragma unroll
    for (int ni = 0; ni < 4; ++ni) {
      const int n  = n0 + wc * 64 + ni * 16 + l15;
      const float bv = bias[n];
#pragma unroll
      for (int mi = 0; mi < 4; ++mi) {
        const int mb = m0 + wr * 64 + mi * 16 + l4 * 4;
#pragma unroll
        for (int r = 0; r < 4; ++r)
          Cf[(size_t)(mb + r) * N + n] = acc[mi][ni][r] + bv;
      }
    }
  }
}

// ---------------- windowed causal attention ----------------
// grid: head*64 blocks; block = 4 waves; wave w owns queries [q0+16w, q0+16w+16)
// keys span [q0-64, q0+64) -> 8 key tiles of 16. Q pre-scaled by 1/8.
__global__ __launch_bounds__(256)
void attn_kernel(const unsigned short* __restrict__ Qb,
                 const unsigned short* __restrict__ Kb,
                 const unsigned short* __restrict__ Vt,
                 unsigned short* __restrict__ att) {
  __shared__ short Pl[4][16][136];   // per-wave P tile, +8 pad (2-way banks only)
  const int h  = blockIdx.x >> 6;
  const int q0 = (blockIdx.x & 63) << 6;
  const int w  = threadIdx.x >> 6;
  const int l  = threadIdx.x & 63;
  const int l15 = l & 15, l4 = l >> 4;
  const int qw = q0 + w * 16;

  const unsigned short* Qh = Qb + (size_t)h * NSEQ * DHEAD;
  const unsigned short* Kh = Kb + (size_t)h * NSEQ * DHEAD;
  const unsigned short* Vh = Vt + (size_t)h * DHEAD * NSEQ;

  short8 aq[2];
  {
    const int qrow = qw + l15;
    aq[0] = *(const short8*)&Qh[(size_t)qrow * DHEAD + l4 * 8];
    aq[1] = *(const short8*)&Qh[(size_t)qrow * DHEAD + 32 + l4 * 8];
  }

  // ---- scores S[16 q][128 j] ----
  f32x4 s[8] = {};
#pragma unroll
  for (int t = 0; t < 8; ++t) {
    int j  = q0 - 64 + t * 16 + l15;
    int jc = j < 0 ? 0 : j;
    short8 b0 = *(const short8*)&Kh[(size_t)jc * DHEAD + l4 * 8];
    short8 b1 = *(const short8*)&Kh[(size_t)jc * DHEAD + 32 + l4 * 8];
    s[t] = __builtin_amdgcn_mfma_f32_16x16x32_bf16(aq[0], b0, s[t], 0, 0, 0);
    s[t] = __builtin_amdgcn_mfma_f32_16x16x32_bf16(aq[1], b1, s[t], 0, 0, 0);
  }

  // ---- mask + softmax (rows fully materialized; 16-lane shfl reduce) ----
  float rmax[4] = {-3e38f, -3e38f, -3e38f, -3e38f};
#pragma unroll
  for (int t = 0; t < 8; ++t)
#pragma unroll
    for (int r = 0; r < 4; ++r) {
      const int i = qw + l4 * 4 + r;
      const int j = q0 - 64 + t * 16 + l15;
      const int diff = i - j;
      float sv = (j >= 0 && diff >= 0 && diff < WIN) ? s[t][r] : -3e38f;
      s[t][r] = sv;
      rmax[r] = fmaxf(rmax[r], sv);
    }
#pragma unroll
  for (int r = 0; r < 4; ++r)
#pragma unroll
    for (int m = 1; m < 16; m <<= 1)
      rmax[r] = fmaxf(rmax[r], __shfl_xor(rmax[r], m, 64));

  float rsum[4] = {0.f, 0.f, 0.f, 0.f};
#pragma unroll
  for (int t = 0; t < 8; ++t)
#pragma unroll
    for (int r = 0; r < 4; ++r) {
      float p = __expf(s[t][r] - rmax[r]);
      s[t][r] = p;
      rsum[r] += p;
    }
#pragma unroll
  for (int r = 0; r < 4; ++r)
#pragma unroll
    for (int m = 1; m < 16; m <<= 1)
      rsum[r] += __shfl_xor(rsum[r], m, 64);

  // ---- P -> LDS (bf16, unnormalized; normalize in epilogue) ----
#pragma unroll
  for (int t = 0; t < 8; ++t)
#pragma unroll
    for (int r = 0; r < 4; ++r)
      Pl[w][l4 * 4 + r][t * 16 + l15] = (short)f2bf(s[t][r]);

  // ---- O = P * V  (V^T layout makes B-operand contiguous) ----
  f32x4 o[4] = {};
#pragma unroll
  for (int ks = 0; ks < 4; ++ks) {
    short8 ap = *(const short8*)&Pl[w][l15][ks * 32 + l4 * 8];
    int jg = q0 - 64 + ks * 32 + l4 * 8;
    if (jg < 0) jg = 0;                       // P==0 there; any V value ok
#pragma unroll
    for (int dt = 0; dt < 4; ++dt) {
      const int d = dt * 16 + l15;
      short8 bv = *(const short8*)&Vh[(size_t)d * NSEQ + jg];
      o[dt] = __builtin_amdgcn_mfma_f32_16x16x32_bf16(ap, bv, o[dt], 0, 0, 0);
    }
  }

#pragma unroll
  for (int r = 0; r < 4; ++r) {
    const float rinv = 1.0f / rsum[r];
    const int m = qw + l4 * 4 + r;
#pragma unroll
    for (int dt = 0; dt < 4; ++dt)
      att[(size_t)m * DM + h * DHEAD + dt * 16 + l15] = f2bf(o[dt][r] * rinv);
  }
}

// ---------------- launch ----------------
extern "C" void kernel_launch(void* const* d_in, const int* in_sizes, int n_in,
                              void* d_out, int out_size, void* d_ws, size_t ws_size,
                              hipStream_t stream) {
  const float* x    = (const float*)d_in[0];
  const float* wqkv = (const float*)d_in[1];
  const float* bqkv = (const float*)d_in[2];
  const float* wout = (const float*)d_in[3];
  const float* bout = (const float*)d_in[4];
  float* out = (float*)d_out;

  unsigned short* ws = (unsigned short*)d_ws;
  unsigned short* xb    = ws;                                  // 4M elems
  unsigned short* wqkvb = xb    + (size_t)NSEQ * DM;           // 3M
  unsigned short* woutb = wqkvb + (size_t)3 * DM * DM;         // 1M
  unsigned short* qb    = woutb + (size_t)DM * DM;             // 4M (scaled Q)
  unsigned short* kb    = qb    + (size_t)NSEQ * DM;           // 4M
  unsigned short* vtb   = kb    + (size_t)NSEQ * DM;           // 4M (V^T per head)
  unsigned short* attb  = vtb   + (size_t)NSEQ * DM;           // 4M
  // total 24M bf16 elems = 48 MB of d_ws

  cvt_kernel<<<(NSEQ * DM / 4 + 255) / 256, 256, 0, stream>>>(x, xb, NSEQ * DM / 4);
  cvt_kernel<<<(3 * DM * DM / 4 + 255) / 256, 256, 0, stream>>>(wqkv, wqkvb, 3 * DM * DM / 4);
  cvt_kernel<<<(DM * DM / 4 + 255) / 256, 256, 0, stream>>>(wout, woutb, DM * DM / 4);

  gemm_bt<0><<<(NSEQ / 128) * (3 * DM / 128), 256, 0, stream>>>(
      xb, wqkvb, bqkv, nullptr, qb, kb, vtb, NSEQ, 3 * DM, DM);

  attn_kernel<<<NHEAD * (NSEQ / 64), 256, 0, stream>>>(qb, kb, vtb, attb);

  gemm_bt<1><<<(NSEQ / 128) * (DM / 128), 256, 0, stream>>>(
      attb, woutb, bout, out, nullptr, nullptr, nullptr, NSEQ, DM, DM);
}